// Round 7
// baseline (124.070 us; speedup 1.0000x reference)
//
#include <hip/hip_runtime.h>
#include <hip/hip_cooperative_groups.h>

namespace cg = cooperative_groups;

typedef float f32x4 __attribute__((ext_vector_type(4)));
typedef short bf16x8 __attribute__((ext_vector_type(8)));
typedef __bf16 bf16x2_t __attribute__((ext_vector_type(2)));
typedef unsigned int u32;
typedef unsigned long long u64;

__device__ __forceinline__ u32 pk2(float a, float b){
  bf16x2_t h; h[0] = (__bf16)a; h[1] = (__bf16)b;
  return __builtin_bit_cast(u32, h);
}
__device__ __forceinline__ unsigned short f2bf(float f){
  __bf16 h = (__bf16)f;
  return __builtin_bit_cast(unsigned short, h);
}
__device__ __forceinline__ float bf2f(unsigned short h){
  u32 u = ((u32)h) << 16;
  return __builtin_bit_cast(float, u);
}

// ws layout in ushort (bf16) units
// Proj weights in MFMA-fragment order:
//   WF[which][ ((kc*4 + cg)*64 + lane)*8 + j ]  = W[k*64+n],
//   n = cg*16 + (lane&15), k = kc*32 + (lane>>4)*8 + j   (kc 0..15, cg 0..3)
#define WS_WF    0u        // 3 x 32768
#define WS_WOFT  98304u    // [512][64]  Wo_foldT[n][k] row-major
#define WS_QP    131072u   // [8192][64]  qp * 0.125*log2(e) folded
#define WS_KP    655360u   // [8192][64]
#define WS_VPT   1179648u  // [4][64][2048]  vp transposed per batch

#define QSCALE 0.18033688011112042f   // 0.125 * log2(e)
#define PSTR 72

__global__ __launch_bounds__(512) void k_fused(
    const float* __restrict__ q, const float* __restrict__ kmat,
    const float* __restrict__ v, const float* __restrict__ Wq,
    const float* __restrict__ bq, const float* __restrict__ Wk,
    const float* __restrict__ bk, const float* __restrict__ Wv,
    const float* __restrict__ bv, const float* __restrict__ Wo,
    const float* __restrict__ bo, float* __restrict__ out,
    unsigned short* __restrict__ wsu){
  cg::grid_group grid = cg::this_grid();
  __shared__ __attribute__((aligned(16))) unsigned char smem[42496];

  const int bid = blockIdx.x;          // 0..255
  const int t   = threadIdx.x;         // 0..511

  // ================= Phase A: prep (weights fold/transpose) ================
  {
    int id = bid*512 + t;              // exactly 131072
    int which = id >> 15;
    int r = id & 32767;
    if (which < 3){
      const float* W = which==0 ? Wq : (which==1 ? Wk : Wv);
      int j   = r & 7;
      int l   = (r >> 3) & 63;
      int cgi = (r >> 9) & 3;
      int kc  = r >> 11;
      int n = cgi*16 + (l & 15);
      int k = kc*32 + (l >> 4)*8 + j;
      wsu[which*32768u + r] = f2bf(W[k*64 + n]);
    } else {
      int n = r >> 6, k = r & 63;
      float s = 0.f;
      #pragma unroll
      for (int h = 0; h < 8; ++h) s += Wo[(h*64 + k)*512 + n];
      wsu[WS_WOFT + r] = f2bf(s);
    }
  }
  grid.sync();

  // ================= Phase B: projection GEMMs =============================
  // groups of 128 threads: grp 0->q, 1->k, 2->v, 3 idle (hits barriers)
  {
    const int grp = t >> 7;
    const int tl  = t & 127;
    const int w2 = tl >> 6, l2 = tl & 63, g2 = l2 >> 4, ln2 = l2 & 15;
    const float* X    = grp==0 ? q  : (grp==1 ? kmat : v);
    const float* bias = grp==0 ? bq : (grp==1 ? bk   : bv);
    const unsigned short* WF = wsu + (grp < 3 ? grp : 0)*32768u;
    unsigned short* Xg = (unsigned short*)(smem + (grp < 3 ? grp : 0)*8192); // 2 bufs x 2048 us
    const int rowbase = bid * 32;

    f32x4 acc[2][2];
    #pragma unroll
    for (int rt = 0; rt < 2; ++rt)
      #pragma unroll
      for (int ntl = 0; ntl < 2; ++ntl) acc[rt][ntl] = (f32x4){0.f,0.f,0.f,0.f};
    float bcol[2] = {0.f, 0.f};
    f32x4 xr[4];
    bf16x8 bc[2][2], bn[2][2];

    if (grp < 3){
      #pragma unroll
      for (int ntl = 0; ntl < 2; ++ntl) bcol[ntl] = bias[(w2*2+ntl)*16 + ln2];
      #pragma unroll
      for (int j = 0; j < 4; ++j){
        int c = tl + j*128; int row = c >> 4, kc = c & 15;
        xr[j] = __builtin_nontemporal_load(reinterpret_cast<const f32x4*>(X + (rowbase+row)*512 + kc*4));
      }
      #pragma unroll
      for (int ntl = 0; ntl < 2; ++ntl)
        #pragma unroll
        for (int kt = 0; kt < 2; ++kt)
          bc[ntl][kt] = *reinterpret_cast<const bf16x8*>(WF + (((0*2+kt)*4 + (w2*2+ntl))*64 + l2)*8);
    }

    #pragma unroll
    for (int i = 0; i < 8; ++i){
      char* Xc = reinterpret_cast<char*>(Xg + (i & 1)*2048);
      if (grp < 3){
        #pragma unroll
        for (int j = 0; j < 4; ++j){
          int c = tl + j*128; int row = c >> 4, kc = c & 15;
          u64 pk = (u64)pk2(xr[j][0], xr[j][1]) | ((u64)pk2(xr[j][2], xr[j][3]) << 32);
          *reinterpret_cast<u64*>(Xc + row*128 + ((kc*8) ^ ((row&7)<<4))) = pk;
        }
        if (i < 7){
          #pragma unroll
          for (int j = 0; j < 4; ++j){
            int c = tl + j*128; int row = c >> 4, kc = c & 15;
            xr[j] = __builtin_nontemporal_load(reinterpret_cast<const f32x4*>(X + (rowbase+row)*512 + (i+1)*64 + kc*4));
          }
        }
      }
      __syncthreads();
      if (grp < 3){
        if (i < 7){
          #pragma unroll
          for (int ntl = 0; ntl < 2; ++ntl)
            #pragma unroll
            for (int kt = 0; kt < 2; ++kt)
              bn[ntl][kt] = *reinterpret_cast<const bf16x8*>(WF + ((((i+1)*2+kt)*4 + (w2*2+ntl))*64 + l2)*8);
        }
        bf16x8 a[2][2];
        #pragma unroll
        for (int rt = 0; rt < 2; ++rt){
          int arow = rt*16 + ln2;
          #pragma unroll
          for (int kt = 0; kt < 2; ++kt)
            a[rt][kt] = *reinterpret_cast<const bf16x8*>(Xc + arow*128 + ((kt*64 + g2*16) ^ ((arow&7)<<4)));
        }
        #pragma unroll
        for (int ntl = 0; ntl < 2; ++ntl)
          #pragma unroll
          for (int kt = 0; kt < 2; ++kt)
            #pragma unroll
            for (int rt = 0; rt < 2; ++rt)
              acc[rt][ntl] = __builtin_amdgcn_mfma_f32_16x16x32_bf16(a[rt][kt], bc[ntl][kt], acc[rt][ntl], 0, 0, 0);
        if (i < 7){
          #pragma unroll
          for (int ntl = 0; ntl < 2; ++ntl)
            #pragma unroll
            for (int kt = 0; kt < 2; ++kt)
              bc[ntl][kt] = bn[ntl][kt];
        }
      }
    }

    if (grp < 2){
      const float sc = (grp==0) ? QSCALE : 1.0f;
      unsigned short* outp = wsu + (grp==0 ? WS_QP : WS_KP);
      #pragma unroll
      for (int rt = 0; rt < 2; ++rt)
        #pragma unroll
        for (int ntl = 0; ntl < 2; ++ntl)
          #pragma unroll
          for (int r = 0; r < 4; ++r)
            outp[(rowbase + rt*16 + g2*4 + r)*64 + (w2*2+ntl)*16 + ln2] = f2bf((acc[rt][ntl][r] + bcol[ntl]) * sc);
    }
    __syncthreads();
    if (grp == 2){
      #pragma unroll
      for (int rt = 0; rt < 2; ++rt)
        #pragma unroll
        for (int ntl = 0; ntl < 2; ++ntl)
          #pragma unroll
          for (int r = 0; r < 4; ++r)
            Xg[(rt*16 + g2*4 + r)*64 + (w2*2+ntl)*16 + ln2] = f2bf(acc[rt][ntl][r] + bcol[ntl]);
    }
    __syncthreads();
    if (grp == 2){
      unsigned short* vpT = wsu + WS_VPT;
      const int b = rowbase >> 11;
      const int kvb = rowbase & 2047;
      const int d = tl >> 1, seg = tl & 1;
      bf16x8 v0, v1;
      #pragma unroll
      for (int i = 0; i < 8; ++i){
        v0[i] = (short)Xg[(seg*16 + i)*64 + d];
        v1[i] = (short)Xg[(seg*16 + 8 + i)*64 + d];
      }
      unsigned short* dst = vpT + ((unsigned)(b*64 + d))*2048u + kvb + seg*16;
      *reinterpret_cast<bf16x8*>(dst)     = v0;
      *reinterpret_cast<bf16x8*>(dst + 8) = v1;
    }
  }
  grid.sync();

  // ================= Phase C: split-KV flash attention + out proj ==========
  {
    const unsigned short* qp   = wsu + WS_QP;
    const unsigned short* kp   = wsu + WS_KP;
    const unsigned short* vpT  = wsu + WS_VPT;
    const unsigned short* WofT = wsu + WS_WOFT;

    const int w = t >> 6, l = t & 63, g = l >> 4, ln = l & 15;
    const int batch = bid >> 6;
    const int qbase = batch*2048 + (bid & 63)*32;

    unsigned short* Pw  = (unsigned short*)(smem + w*4608);
    float*          pls = (float*)(smem + 36864);
    unsigned short* ob  = (unsigned short*)(smem + 37888);

    bf16x8 qa[2][2];
    #pragma unroll
    for (int rt = 0; rt < 2; ++rt)
      #pragma unroll
      for (int kt = 0; kt < 2; ++kt)
        qa[rt][kt] = *reinterpret_cast<const bf16x8*>(qp + (qbase + rt*16 + ln)*64 + kt*32 + g*8);

    f32x4 o[4][2];
    #pragma unroll
    for (int dt = 0; dt < 4; ++dt)
      #pragma unroll
      for (int rt = 0; rt < 2; ++rt) o[dt][rt] = (f32x4){0.f,0.f,0.f,0.f};
    float ls[2] = {0.f, 0.f};

    const unsigned short* kpb = kp  + batch*2048*64;
    const unsigned short* vpb = vpT + batch*64*2048;
    const int kv0 = w * 256;

    #pragma unroll
    for (int it = 0; it < 4; ++it){
      const int kvb = kv0 + it*64;
      bf16x8 ka[4][2];
      #pragma unroll
      for (int ct = 0; ct < 4; ++ct)
        #pragma unroll
        for (int kt = 0; kt < 2; ++kt)
          ka[ct][kt] = *reinterpret_cast<const bf16x8*>(kpb + (kvb + ct*16 + ln)*64 + kt*32 + g*8);
      f32x4 st[4][2];
      #pragma unroll
      for (int ct = 0; ct < 4; ++ct)
        #pragma unroll
        for (int rt = 0; rt < 2; ++rt){
          st[ct][rt] = (f32x4){0.f,0.f,0.f,0.f};
          #pragma unroll
          for (int kt = 0; kt < 2; ++kt)
            st[ct][rt] = __builtin_amdgcn_mfma_f32_16x16x32_bf16(ka[ct][kt], qa[rt][kt], st[ct][rt], 0,0,0);
        }
      bf16x8 vb[4][2];
      #pragma unroll
      for (int dt = 0; dt < 4; ++dt)
        #pragma unroll
        for (int kvt = 0; kvt < 2; ++kvt)
          vb[dt][kvt] = *reinterpret_cast<const bf16x8*>(vpb + (dt*16 + ln)*2048 + kvb + kvt*32 + g*8);

      #pragma unroll
      for (int rt = 0; rt < 2; ++rt){
        float p[4][4];
        float rs = 0.f;
        #pragma unroll
        for (int ct = 0; ct < 4; ++ct)
          #pragma unroll
          for (int r = 0; r < 4; ++r){
            p[ct][r] = exp2f(st[ct][rt][r]);
            rs += p[ct][r];
          }
        rs += __shfl_xor(rs, 16, 64);
        rs += __shfl_xor(rs, 32, 64);
        ls[rt] += rs;
        unsigned short* pr = Pw + (rt*16 + ln)*PSTR;
        #pragma unroll
        for (int ct = 0; ct < 4; ++ct){
          *reinterpret_cast<u32*>(pr + ct*16 + g*4)     = pk2(p[ct][0], p[ct][1]);
          *reinterpret_cast<u32*>(pr + ct*16 + g*4 + 2) = pk2(p[ct][2], p[ct][3]);
        }
      }
      bf16x8 pb[2][2];
      #pragma unroll
      for (int rt = 0; rt < 2; ++rt)
        #pragma unroll
        for (int kvt = 0; kvt < 2; ++kvt)
          pb[rt][kvt] = *reinterpret_cast<const bf16x8*>(Pw + (rt*16 + ln)*PSTR + kvt*32 + g*8);
      #pragma unroll
      for (int dt = 0; dt < 4; ++dt)
        #pragma unroll
        for (int rt = 0; rt < 2; ++rt)
          #pragma unroll
          for (int kvt = 0; kvt < 2; ++kvt)
            o[dt][rt] = __builtin_amdgcn_mfma_f32_16x16x32_bf16(vb[dt][kvt], pb[rt][kvt], o[dt][rt], 0,0,0);
    }

    if (l < 16){ pls[w*32 + ln] = ls[0]; pls[w*32 + 16 + ln] = ls[1]; }
    unsigned short* pow_ = (unsigned short*)(smem + w*4608);
    #pragma unroll
    for (int dt = 0; dt < 4; ++dt)
      #pragma unroll
      for (int rt = 0; rt < 2; ++rt){
        u32* dst = reinterpret_cast<u32*>(pow_ + (rt*16 + ln)*68 + dt*16 + g*4);
        dst[0] = pk2(o[dt][rt][0], o[dt][rt][1]);
        dst[1] = pk2(o[dt][rt][2], o[dt][rt][3]);
      }
    __syncthreads();

    #pragma unroll
    for (int i = 0; i < 4; ++i){
      int idx = t + i*512;
      int row = idx >> 6, d = idx & 63;
      float den = 0.f, num = 0.f;
      #pragma unroll
      for (int w2i = 0; w2i < 8; ++w2i){
        den += pls[w2i*32 + row];
        num += bf2f(*((const unsigned short*)(smem + w2i*4608) + row*68 + d));
      }
      ob[row*PSTR + d] = f2bf(num / den);
    }
    __syncthreads();

    const int colbase = w*64;
    bf16x8 ao[2][2];
    #pragma unroll
    for (int rt = 0; rt < 2; ++rt)
      #pragma unroll
      for (int kt = 0; kt < 2; ++kt)
        ao[rt][kt] = *reinterpret_cast<const bf16x8*>(ob + (rt*16 + ln)*PSTR + kt*32 + g*8);
    f32x4 oc[2][4];
    #pragma unroll
    for (int rt = 0; rt < 2; ++rt)
      #pragma unroll
      for (int nt = 0; nt < 4; ++nt) oc[rt][nt] = (f32x4){0.f,0.f,0.f,0.f};
    #pragma unroll
    for (int nt = 0; nt < 4; ++nt){
      #pragma unroll
      for (int kt = 0; kt < 2; ++kt){
        bf16x8 b = *reinterpret_cast<const bf16x8*>(WofT + (colbase + nt*16 + ln)*64 + kt*32 + g*8);
        #pragma unroll
        for (int rt = 0; rt < 2; ++rt)
          oc[rt][nt] = __builtin_amdgcn_mfma_f32_16x16x32_bf16(ao[rt][kt], b, oc[rt][nt], 0,0,0);
      }
    }
    #pragma unroll
    for (int nt = 0; nt < 4; ++nt){
      float bc = bo[colbase + nt*16 + ln];
      #pragma unroll
      for (int rt = 0; rt < 2; ++rt){
        #pragma unroll
        for (int r = 0; r < 4; ++r){
          int row = qbase + rt*16 + g*4 + r;
          __builtin_nontemporal_store(oc[rt][nt][r] + bc, &out[row*512 + colbase + nt*16 + ln]);
        }
      }
    }
  }
}

extern "C" void kernel_launch(void* const* d_in, const int* in_sizes, int n_in,
                              void* d_out, int out_size, void* d_ws, size_t ws_size,
                              hipStream_t stream){
  const float* q  = (const float*)d_in[0];
  const float* k  = (const float*)d_in[1];
  const float* v  = (const float*)d_in[2];
  const float* Wq = (const float*)d_in[3];
  const float* bq = (const float*)d_in[4];
  const float* Wk = (const float*)d_in[5];
  const float* bk = (const float*)d_in[6];
  const float* Wv = (const float*)d_in[7];
  const float* bv = (const float*)d_in[8];
  const float* Wo = (const float*)d_in[9];
  const float* bo = (const float*)d_in[10];
  float* out = (float*)d_out;
  unsigned short* wsu = (unsigned short*)d_ws;

  void* args[13] = { (void*)&q, (void*)&k, (void*)&v, (void*)&Wq, (void*)&bq,
                     (void*)&Wk, (void*)&bk, (void*)&Wv, (void*)&bv, (void*)&Wo,
                     (void*)&bo, (void*)&out, (void*)&wsu };
  hipLaunchCooperativeKernel((void*)k_fused, dim3(256), dim3(512), args, 0, stream);
}

// Round 8
// 43.954 us; speedup vs baseline: 2.8227x; 2.8227x over previous
//
#include <hip/hip_runtime.h>

typedef float f32x4 __attribute__((ext_vector_type(4)));
typedef short bf16x8 __attribute__((ext_vector_type(8)));
typedef __bf16 bf16x2_t __attribute__((ext_vector_type(2)));
typedef unsigned int u32;
typedef unsigned long long u64;

__device__ __forceinline__ u32 pk2(float a, float b){
  bf16x2_t h; h[0] = (__bf16)a; h[1] = (__bf16)b;
  return __builtin_bit_cast(u32, h);
}
__device__ __forceinline__ unsigned short f2bf(float f){
  __bf16 h = (__bf16)f;
  return __builtin_bit_cast(unsigned short, h);
}
__device__ __forceinline__ float bf2f(unsigned short h){
  u32 u = ((u32)h) << 16;
  return __builtin_bit_cast(float, u);
}

// ws layout in ushort (bf16) units
#define WS_WOFT  98304u    // [512][64]  Wo_foldT[n][k] row-major
#define WS_QP    131072u   // [8192][64]  qp * 0.125*log2(e) folded
#define WS_KP    655360u   // [8192][64]
#define WS_VPT   1179648u  // [4][64][2048]  vp transposed per batch

#define QSCALE 0.18033688011112042f   // 0.125 * log2(e)

// B-fragment gather straight from fp32 W (row-major [512][64], L2-resident):
// fragment (kc, cg): lane l, elem j  ->  W[(kc*32 + (l>>4)*8 + j)*64 + cg*16 + (l&15)]
__device__ __forceinline__ bf16x8 wfrag(const float* __restrict__ W, int kc, int cg,
                                        int g, int ln){
  const float* p = W + (size_t)(kc*32 + g*8)*64 + cg*16 + ln;
  union { bf16x8 v8; u32 w[4]; } u;
  #pragma unroll
  for (int j = 0; j < 4; ++j)
    u.w[j] = pk2(p[(2*j)*64], p[(2*j+1)*64]);
  return u.v8;
}

// ---------------- K1: projection GEMMs + Wo fold (grid 256 x 4) -------------
// y = 0/1/2 : X @ W for q/k/v (32 rows/block, 128 threads, dbuf LDS)
// y = 3     : Wo_foldT (1 element/thread)
__global__ __launch_bounds__(128) void k_proj(const float* __restrict__ q,
    const float* __restrict__ kmat, const float* __restrict__ v,
    const float* __restrict__ bq, const float* __restrict__ bk,
    const float* __restrict__ bv, const float* __restrict__ Wq,
    const float* __restrict__ Wk, const float* __restrict__ Wv,
    const float* __restrict__ Wo, unsigned short* __restrict__ wsu){
  const int which = blockIdx.y;
  if (which == 3){
    int r = blockIdx.x*128 + threadIdx.x;     // exactly 32768
    int n = r >> 6, k = r & 63;               // Wo_foldT[n][k] = sum_h Wo[h*64+k][n]
    float s = 0.f;
    #pragma unroll
    for (int h = 0; h < 8; ++h) s += Wo[(h*64 + k)*512 + n];
    wsu[WS_WOFT + r] = f2bf(s);
    return;
  }

  __shared__ unsigned short Xs[2][2048];      // 2 x (32 rows x 64 k) bf16, XOR-swizzled
  const float* X    = which==0 ? q  : (which==1 ? kmat : v);
  const float* bias = which==0 ? bq : (which==1 ? bk   : bv);
  const float* W    = which==0 ? Wq : (which==1 ? Wk   : Wv);
  const int rowbase = blockIdx.x * 32;
  const int t = threadIdx.x;
  const int w = t >> 6, l = t & 63, g = l >> 4, ln = l & 15;

  f32x4 acc[2][2];                            // [rt][ntl]
  #pragma unroll
  for (int rt = 0; rt < 2; ++rt)
    #pragma unroll
    for (int ntl = 0; ntl < 2; ++ntl) acc[rt][ntl] = (f32x4){0.f,0.f,0.f,0.f};
  float bcol[2];
  #pragma unroll
  for (int ntl = 0; ntl < 2; ++ntl) bcol[ntl] = bias[(w*2+ntl)*16 + ln];

  f32x4 xr[4];
  bf16x8 bc[2][2], bn[2][2];

  // prologue: chunk 0 X + B
  #pragma unroll
  for (int j = 0; j < 4; ++j){
    int c = t + j*128; int row = c >> 4, kc = c & 15;
    xr[j] = __builtin_nontemporal_load(reinterpret_cast<const f32x4*>(X + (rowbase+row)*512 + kc*4));
  }
  #pragma unroll
  for (int ntl = 0; ntl < 2; ++ntl)
    #pragma unroll
    for (int kt = 0; kt < 2; ++kt)
      bc[ntl][kt] = wfrag(W, 0*2+kt, w*2+ntl, g, ln);

  #pragma unroll
  for (int i = 0; i < 8; ++i){
    char* Xc = reinterpret_cast<char*>(Xs[i & 1]);
    // stage current chunk regs -> LDS (convert)
    #pragma unroll
    for (int j = 0; j < 4; ++j){
      int c = t + j*128; int row = c >> 4, kc = c & 15;
      u64 pk = (u64)pk2(xr[j][0], xr[j][1]) | ((u64)pk2(xr[j][2], xr[j][3]) << 32);
      *reinterpret_cast<u64*>(Xc + row*128 + ((kc*8) ^ ((row&7)<<4))) = pk;
    }
    // issue next chunk loads
    if (i < 7){
      #pragma unroll
      for (int j = 0; j < 4; ++j){
        int c = t + j*128; int row = c >> 4, kc = c & 15;
        xr[j] = __builtin_nontemporal_load(reinterpret_cast<const f32x4*>(X + (rowbase+row)*512 + (i+1)*64 + kc*4));
      }
    }
    __syncthreads();
    if (i < 7){
      #pragma unroll
      for (int ntl = 0; ntl < 2; ++ntl)
        #pragma unroll
        for (int kt = 0; kt < 2; ++kt)
          bn[ntl][kt] = wfrag(W, (i+1)*2+kt, w*2+ntl, g, ln);
    }
    bf16x8 a[2][2];
    #pragma unroll
    for (int rt = 0; rt < 2; ++rt){
      int arow = rt*16 + ln;
      #pragma unroll
      for (int kt = 0; kt < 2; ++kt)
        a[rt][kt] = *reinterpret_cast<const bf16x8*>(Xc + arow*128 + ((kt*64 + g*16) ^ ((arow&7)<<4)));
    }
    #pragma unroll
    for (int ntl = 0; ntl < 2; ++ntl)
      #pragma unroll
      for (int kt = 0; kt < 2; ++kt)
        #pragma unroll
        for (int rt = 0; rt < 2; ++rt)
          acc[rt][ntl] = __builtin_amdgcn_mfma_f32_16x16x32_bf16(a[rt][kt], bc[ntl][kt], acc[rt][ntl], 0, 0, 0);
    if (i < 7){
      #pragma unroll
      for (int ntl = 0; ntl < 2; ++ntl)
        #pragma unroll
        for (int kt = 0; kt < 2; ++kt)
          bc[ntl][kt] = bn[ntl][kt];
    }
  }

  if (which < 2){
    const float sc = (which==0) ? QSCALE : 1.0f;
    unsigned short* outp = wsu + (which==0 ? WS_QP : WS_KP);
    #pragma unroll
    for (int rt = 0; rt < 2; ++rt)
      #pragma unroll
      for (int ntl = 0; ntl < 2; ++ntl)
        #pragma unroll
        for (int r = 0; r < 4; ++r)
          outp[(rowbase + rt*16 + g*4 + r)*64 + (w*2+ntl)*16 + ln] = f2bf((acc[rt][ntl][r] + bcol[ntl]) * sc);
  } else {
    // V: round-trip through LDS, store transposed vpT[b][d][kv]
    __syncthreads();
    #pragma unroll
    for (int rt = 0; rt < 2; ++rt)
      #pragma unroll
      for (int ntl = 0; ntl < 2; ++ntl)
        #pragma unroll
        for (int r = 0; r < 4; ++r)
          Xs[0][(rt*16 + g*4 + r)*64 + (w*2+ntl)*16 + ln] = f2bf(acc[rt][ntl][r] + bcol[ntl]);
    __syncthreads();
    unsigned short* vpT = wsu + WS_VPT;
    const int b = rowbase >> 11;
    const int kvb = rowbase & 2047;
    const int d = t >> 1, seg = t & 1;        // 64 d x 2 segs of 16 kv
    bf16x8 v0, v1;
    #pragma unroll
    for (int i = 0; i < 8; ++i){
      v0[i] = (short)Xs[0][(seg*16 + i)*64 + d];
      v1[i] = (short)Xs[0][(seg*16 + 8 + i)*64 + d];
    }
    unsigned short* dst = vpT + ((unsigned)(b*64 + d))*2048u + kvb + seg*16;
    *reinterpret_cast<bf16x8*>(dst)     = v0;
    *reinterpret_cast<bf16x8*>(dst + 8) = v1;
  }
}

// ---------------- K2: split-KV flash attention + fused output projection ----
// Identical to round-6 k_attn.
#define PSTR 72

__global__ __launch_bounds__(512) void k_attn(const unsigned short* __restrict__ wsu,
    const float* __restrict__ bo, float* __restrict__ out){
  __shared__ __attribute__((aligned(16))) unsigned char smem[42496];

  const unsigned short* qp   = wsu + WS_QP;
  const unsigned short* kp   = wsu + WS_KP;
  const unsigned short* vpT  = wsu + WS_VPT;
  const unsigned short* WofT = wsu + WS_WOFT;

  const int t = threadIdx.x;
  const int w = t >> 6, l = t & 63, g = l >> 4, ln = l & 15;
  const int batch = blockIdx.y;
  const int qbase = batch*2048 + blockIdx.x*32;

  unsigned short* Pw  = (unsigned short*)(smem + w*4608);
  float*          pls = (float*)(smem + 36864);
  unsigned short* ob  = (unsigned short*)(smem + 37888);

  bf16x8 qa[2][2];
  #pragma unroll
  for (int rt = 0; rt < 2; ++rt)
    #pragma unroll
    for (int kt = 0; kt < 2; ++kt)
      qa[rt][kt] = *reinterpret_cast<const bf16x8*>(qp + (qbase + rt*16 + ln)*64 + kt*32 + g*8);

  f32x4 o[4][2];
  #pragma unroll
  for (int dt = 0; dt < 4; ++dt)
    #pragma unroll
    for (int rt = 0; rt < 2; ++rt) o[dt][rt] = (f32x4){0.f,0.f,0.f,0.f};
  float ls[2] = {0.f, 0.f};

  const unsigned short* kpb = kp  + batch*2048*64;
  const unsigned short* vpb = vpT + batch*64*2048;
  const int kv0 = w * 256;

  #pragma unroll
  for (int it = 0; it < 4; ++it){
    const int kvb = kv0 + it*64;
    bf16x8 ka[4][2];
    #pragma unroll
    for (int ct = 0; ct < 4; ++ct)
      #pragma unroll
      for (int kt = 0; kt < 2; ++kt)
        ka[ct][kt] = *reinterpret_cast<const bf16x8*>(kpb + (kvb + ct*16 + ln)*64 + kt*32 + g*8);
    f32x4 st[4][2];
    #pragma unroll
    for (int ct = 0; ct < 4; ++ct)
      #pragma unroll
      for (int rt = 0; rt < 2; ++rt){
        st[ct][rt] = (f32x4){0.f,0.f,0.f,0.f};
        #pragma unroll
        for (int kt = 0; kt < 2; ++kt)
          st[ct][rt] = __builtin_amdgcn_mfma_f32_16x16x32_bf16(ka[ct][kt], qa[rt][kt], st[ct][rt], 0,0,0);
      }
    bf16x8 vb[4][2];
    #pragma unroll
    for (int dt = 0; dt < 4; ++dt)
      #pragma unroll
      for (int kvt = 0; kvt < 2; ++kvt)
        vb[dt][kvt] = *reinterpret_cast<const bf16x8*>(vpb + (dt*16 + ln)*2048 + kvb + kvt*32 + g*8);

    #pragma unroll
    for (int rt = 0; rt < 2; ++rt){
      float p[4][4];
      float rs = 0.f;
      #pragma unroll
      for (int ct = 0; ct < 4; ++ct)
        #pragma unroll
        for (int r = 0; r < 4; ++r){
          p[ct][r] = exp2f(st[ct][rt][r]);
          rs += p[ct][r];
        }
      rs += __shfl_xor(rs, 16, 64);
      rs += __shfl_xor(rs, 32, 64);
      ls[rt] += rs;
      unsigned short* pr = Pw + (rt*16 + ln)*PSTR;
      #pragma unroll
      for (int ct = 0; ct < 4; ++ct){
        *reinterpret_cast<u32*>(pr + ct*16 + g*4)     = pk2(p[ct][0], p[ct][1]);
        *reinterpret_cast<u32*>(pr + ct*16 + g*4 + 2) = pk2(p[ct][2], p[ct][3]);
      }
    }
    bf16x8 pb[2][2];
    #pragma unroll
    for (int rt = 0; rt < 2; ++rt)
      #pragma unroll
      for (int kvt = 0; kvt < 2; ++kvt)
        pb[rt][kvt] = *reinterpret_cast<const bf16x8*>(Pw + (rt*16 + ln)*PSTR + kvt*32 + g*8);
    #pragma unroll
    for (int dt = 0; dt < 4; ++dt)
      #pragma unroll
      for (int rt = 0; rt < 2; ++rt)
        #pragma unroll
        for (int kvt = 0; kvt < 2; ++kvt)
          o[dt][rt] = __builtin_amdgcn_mfma_f32_16x16x32_bf16(vb[dt][kvt], pb[rt][kvt], o[dt][rt], 0,0,0);
  }

  if (l < 16){ pls[w*32 + ln] = ls[0]; pls[w*32 + 16 + ln] = ls[1]; }
  unsigned short* pow_ = (unsigned short*)(smem + w*4608);
  #pragma unroll
  for (int dt = 0; dt < 4; ++dt)
    #pragma unroll
    for (int rt = 0; rt < 2; ++rt){
      u32* dst = reinterpret_cast<u32*>(pow_ + (rt*16 + ln)*68 + dt*16 + g*4);
      dst[0] = pk2(o[dt][rt][0], o[dt][rt][1]);
      dst[1] = pk2(o[dt][rt][2], o[dt][rt][3]);
    }
  __syncthreads();

  #pragma unroll
  for (int i = 0; i < 4; ++i){
    int idx = t + i*512;
    int row = idx >> 6, d = idx & 63;
    float den = 0.f, num = 0.f;
    #pragma unroll
    for (int w2 = 0; w2 < 8; ++w2){
      den += pls[w2*32 + row];
      num += bf2f(*((const unsigned short*)(smem + w2*4608) + row*68 + d));
    }
    ob[row*PSTR + d] = f2bf(num / den);
  }
  __syncthreads();

  const int colbase = w*64;
  bf16x8 ao[2][2];
  #pragma unroll
  for (int rt = 0; rt < 2; ++rt)
    #pragma unroll
    for (int kt = 0; kt < 2; ++kt)
      ao[rt][kt] = *reinterpret_cast<const bf16x8*>(ob + (rt*16 + ln)*PSTR + kt*32 + g*8);
  f32x4 oc[2][4];
  #pragma unroll
  for (int rt = 0; rt < 2; ++rt)
    #pragma unroll
    for (int nt = 0; nt < 4; ++nt) oc[rt][nt] = (f32x4){0.f,0.f,0.f,0.f};
  #pragma unroll
  for (int nt = 0; nt < 4; ++nt){
    #pragma unroll
    for (int kt = 0; kt < 2; ++kt){
      bf16x8 b = *reinterpret_cast<const bf16x8*>(WofT + (colbase + nt*16 + ln)*64 + kt*32 + g*8);
      #pragma unroll
      for (int rt = 0; rt < 2; ++rt)
        oc[rt][nt] = __builtin_amdgcn_mfma_f32_16x16x32_bf16(ao[rt][kt], b, oc[rt][nt], 0,0,0);
    }
  }
  #pragma unroll
  for (int nt = 0; nt < 4; ++nt){
    float bc = bo[colbase + nt*16 + ln];
    #pragma unroll
    for (int rt = 0; rt < 2; ++rt){
      #pragma unroll
      for (int r = 0; r < 4; ++r){
        int row = qbase + rt*16 + g*4 + r;
        __builtin_nontemporal_store(oc[rt][nt][r] + bc, &out[row*512 + colbase + nt*16 + ln]);
      }
    }
  }
}

extern "C" void kernel_launch(void* const* d_in, const int* in_sizes, int n_in,
                              void* d_out, int out_size, void* d_ws, size_t ws_size,
                              hipStream_t stream){
  const float* q  = (const float*)d_in[0];
  const float* k  = (const float*)d_in[1];
  const float* v  = (const float*)d_in[2];
  const float* Wq = (const float*)d_in[3];
  const float* bq = (const float*)d_in[4];
  const float* Wk = (const float*)d_in[5];
  const float* bk = (const float*)d_in[6];
  const float* Wv = (const float*)d_in[7];
  const float* bv = (const float*)d_in[8];
  const float* Wo = (const float*)d_in[9];
  const float* bo = (const float*)d_in[10];
  float* out = (float*)d_out;
  unsigned short* wsu = (unsigned short*)d_ws;

  k_proj<<<dim3(256, 4), dim3(128), 0, stream>>>(q, k, v, bq, bk, bv, Wq, Wk, Wv, Wo, wsu);
  k_attn<<<dim3(64, 4), dim3(512), 0, stream>>>(wsu, bo, out);
}